// Round 10
// baseline (8721.234 us; speedup 1.0000x reference)
//
#include <hip/hip_runtime.h>

#define T_LEN 512
#define BATCH 64
#define HID   512
#define EMB   512
#define NWG   256
#define TPB   512
#define RING_SLOT (HID * BATCH)   // 32768 floats per slot, layout [j][b]

// ---- grid barrier state (lives in d_ws, zeroed by init kernel) ----
// Monotonic counters (never reset): leaf[g] gets 16 incs/slot, root gets 16.
// Release fans out: epoch (root winner) -> gep[g] (group winners).
struct GBar {
  int leaf[16 * 32];   // arrival counter per group, one cacheline apart
  int root; int pad1[31];
  int epoch; int pad2[31];
  int gep[16 * 32];    // per-group release epoch, one cacheline apart
};

__global__ void init_ws_kernel(int* ws, int n) {
  int stride = gridDim.x * blockDim.x;
  for (int i = blockIdx.x * blockDim.x + threadIdx.x; i < n; i += stride) ws[i] = 0;
}

__device__ __forceinline__ float sigm(float x)      { return 1.f / (1.f + __expf(-x)); }
// saturation-safe tanh: x->+inf => 1, x->-inf => -1, no inf/inf NaN
__device__ __forceinline__ float tanh_fast(float x) { return 1.f - 2.f / (__expf(2.f * x) + 1.f); }

// coherent (device-scope, cache-bypassing) scalar store — no fences needed
__device__ __forceinline__ void cstore(float* p, float v) {
  __hip_atomic_store(p, v, __ATOMIC_RELAXED, __HIP_MEMORY_SCOPE_AGENT);
}

// ---- coherent 8B load, fire-and-forget (NO waitcnt): sc0 sc1 bypass L1/L2
// so no stale lines are possible; completion enforced by WAIT_VM below.
// Panel rows are 64 floats apart (256 B), so offset = I*256.
template <int I, int N>
struct Issue16F2 {
  static __device__ __forceinline__ void go(float2* dst, const float* p) {
    asm volatile("global_load_dwordx2 %0, %1, off offset:%2 sc0 sc1"
                 : "=v"(dst[I]) : "v"(p), "i"(I * 256));
    Issue16F2<I + 1, N>::go(dst, p);
  }
};
template <int N>
struct Issue16F2<N, N> {
  static __device__ __forceinline__ void go(float2*, const float*) {}
};

// s_waitcnt vmcnt(n) as a hard scheduling fence (asm-volatile mutual order +
// sched_barrier(0) pins the consuming FMAs). vmcnt is FIFO: waiting to <=16
// after issuing the next 16 loads guarantees the previous 16 have landed.
#define WAIT_VM(n) do {                                     \
    __builtin_amdgcn_sched_barrier(0);                      \
    asm volatile("s_waitcnt vmcnt(" #n ")" ::: "memory");   \
    __builtin_amdgcn_sched_barrier(0);                      \
  } while (0)

// acc (scalar) += dot(xv, wv)
#define DOT_ACC(a, xv, wv) \
  a = fmaf((xv).w, (wv).w, fmaf((xv).z, (wv).z, fmaf((xv).y, (wv).y, fmaf((xv).x, (wv).x, (a)))))
// acc (float2 over b) += s * v (float2 over b)
#define AXPY2(acc, s, v) do { \
  (acc).x = fmaf((s), (v).x, (acc).x); \
  (acc).y = fmaf((s), (v).y, (acc).y); } while (0)

__global__ __launch_bounds__(TPB, 2) void lstm_pipe(
    const int* __restrict__ src, const int* __restrict__ sen_len,
    const float* __restrict__ emb,
    const float* __restrict__ Wih0, const float* __restrict__ Whh0,
    const float* __restrict__ bih0, const float* __restrict__ bhh0,
    const float* __restrict__ Wih1, const float* __restrict__ Whh1,
    const float* __restrict__ bih1, const float* __restrict__ bhh1,
    float* __restrict__ out,
    int* __restrict__ barp, float* __restrict__ h0ring, float* __restrict__ h1ring)
{
  extern __shared__ char smem_raw[];
  float4* WlV  = (float4*)smem_raw;             // 8192 float4 = 128 KB: [kc][32 rows]
  float*  part = (float*)(smem_raw + 131072);   // 4096 floats =  16 KB: [kh][row32][b32]
  GBar* bar = (GBar*)barp;

  const int wg    = blockIdx.x;
  const int layer = wg >> 7;       // 0: WGs 0..127 (layer0 @ t=s), 1: layer1 @ t=s-1
  const int w7    = wg & 127;
  const int jsl   = w7 >> 1;       // 64 j-slices of 8 j
  const int bhalf = w7 & 1;        // batch half: 32 batches
  const int j0    = jsl << 3;
  const int bbase = bhalf << 5;
  const int tid   = threadIdx.x;
  const int kh    = tid >> 7;      // 0..3  K-segment of 256
  const int lane7 = tid & 127;
  const int bg    = lane7 >> 3;    // 0..15 batch-pair index (2 batches)
  const int rg    = lane7 & 7;     // 0..7  j within slice (jj)
  const int b0    = bbase + (bg << 1);
  const int k0    = kh << 8;       // K range [k0, k0+256)

  const float* Wih = layer ? Wih1 : Wih0;
  const float* Whh = layer ? Whh1 : Whh0;

  // Stage 32 gate-rows x 1024 K of fused [Wih | Whh] into LDS, [kc][32] float4.
  for (int idx = tid; idx < 8192; idx += TPB) {
    int r32 = idx & 31;           // q*8 + jj
    int kc  = idx >> 5;           // 0..255
    int q = r32 >> 3, jj = r32 & 7;
    int grow = q * HID + j0 + jj; // global gate row
    int k4 = kc << 2;
    float4 v;
    if (k4 < EMB) v = *(const float4*)(Wih + (size_t)grow * EMB + k4);
    else          v = *(const float4*)(Whh + (size_t)grow * HID + (k4 - EMB));
    WlV[kc * 32 + r32] = v;
  }

  // Activation-phase identity: threads 0..255 own cell (jj, bl); c lives here.
  const int p_jj = tid >> 5;      // 0..7  (only meaningful for tid<256)
  const int p_bl = tid & 31;      // 0..31
  float bias4[4] = {0.f, 0.f, 0.f, 0.f};
  float c = 0.f;
  int   slen = -2;
  if (tid < 256) {
#pragma unroll
    for (int q = 0; q < 4; ++q) {
      int r = q * HID + j0 + p_jj;
      bias4[q] = layer ? (bih1[r] + bhh1[r]) : (bih0[r] + bhh0[r]);
    }
    slen = sen_len[bbase + p_bl];
  }
  __syncthreads();

  for (int s = 0; s <= T_LEN; ++s) {
    const bool active = (layer == 0) ? (s < T_LEN) : (s >= 1);
    if (active) {
      const int t = (layer == 0) ? s : (s - 1);
      float2 acc[4];
#pragma unroll
      for (int q = 0; q < 4; ++q) acc[q] = make_float2(0.f, 0.f);

      if (layer == 0 && kh < 2) {
        // ---- embedding-gather mode: read-only, normal cached loads ----
        const int* st = src + t * BATCH + b0;
        const float* e0 = emb + (size_t)st[0] * EMB;
        const float* e1 = emb + (size_t)st[1] * EMB;
#pragma unroll 4
        for (int kk = 0; kk < 256; kk += 4) {
          const int k  = k0 + kk;
          const int kc = k >> 2;
          float4 x0 = *(const float4*)(e0 + k);
          float4 x1 = *(const float4*)(e1 + k);
#pragma unroll
          for (int q = 0; q < 4; ++q) {
            float4 wq = WlV[kc * 32 + (q << 3) + rg];
            DOT_ACC(acc[q].x, x0, wq);
            DOT_ACC(acc[q].y, x1, wq);
          }
        }
      } else {
        // ---- transposed-ring mode: coherent dwordx2 loads, SW-pipelined ----
        const float* xT;
        if (layer == 0) {
          // own h_{t-1}: K 512..1023 (kh = 2,3)
          xT = h0ring + ((s + 1) & 1) * RING_SLOT + (k0 - EMB) * BATCH;
        } else if (kh < 2) {
          // h0_t from layer 0 (produced at slot s-1): K 0..511
          xT = h0ring + ((s - 1) & 1) * RING_SLOT + k0 * BATCH;
        } else {
          // own h1_{t-1}: K 512..1023
          xT = h1ring + ((s - 1) & 1) * RING_SLOT + (k0 - EMB) * BATCH;
        }
        const float* p = xT + b0;   // float2 at p + kk*BATCH, kk in [0,256)

        float2 xa[16], xb[16];
        Issue16F2<0, 16>::go(xa, p);               // group 0 in flight
#pragma unroll
        for (int g = 0; g < 16; ++g) {
          float2* cur = (g & 1) ? xb : xa;
          float2* nxt = (g & 1) ? xa : xb;
          if (g < 15) {
            Issue16F2<0, 16>::go(nxt, p + (g + 1) * 16 * BATCH);
            WAIT_VM(16);   // oldest 16 (cur) complete; newest 16 still flying
          } else {
            WAIT_VM(0);
          }
#pragma unroll
          for (int ib = 0; ib < 4; ++ib) {
            const int kc = (k0 + (g << 4) + (ib << 2)) >> 2;
#pragma unroll
            for (int q = 0; q < 4; ++q) {
              float4 wq = WlV[kc * 32 + (q << 3) + rg];
              AXPY2(acc[q], wq.x, cur[(ib << 2) + 0]);
              AXPY2(acc[q], wq.y, cur[(ib << 2) + 1]);
              AXPY2(acc[q], wq.z, cur[(ib << 2) + 2]);
              AXPY2(acc[q], wq.w, cur[(ib << 2) + 3]);
            }
          }
        }
      }
      // write partials: part[kh][row32][b32], row = q*8+rg, b-pair at (bg-bbase-rel)*2
#pragma unroll
      for (int q = 0; q < 4; ++q)
        *(float2*)(part + (kh << 10) + (((q << 3) + rg) << 5) + (bg << 1)) = acc[q];
    }

    __syncthreads();  // partials visible

    if (active && tid < 256) {
      float g4[4];
#pragma unroll
      for (int q = 0; q < 4; ++q) {
        float a = bias4[q];
        const int base = (((q << 3) + p_jj) << 5) + p_bl;
#pragma unroll
        for (int kk = 0; kk < 4; ++kk) a += part[(kk << 10) + base];
        g4[q] = a;
      }
      float ig = sigm(g4[0]), fg = sigm(g4[1]), gg = tanh_fast(g4[2]), og = sigm(g4[3]);
      c = fmaf(fg, c, ig * gg);
      float h = og * tanh_fast(c);
      float* ring = (layer == 0 ? h0ring : h1ring) + (s & 1) * RING_SLOT;
      cstore(ring + (j0 + p_jj) * BATCH + bbase + p_bl, h);  // coherent [j][b]
      if (layer == 1) {
        const int t = s - 1;
        if (t == slen - 1) out[(bbase + p_bl) * HID + j0 + p_jj] = h;
      }
    }

    // ---- hierarchical grid barrier, all-RELAXED, monotonic counters ----
    // __syncthreads() drains vmcnt(0): every coherent h-store is committed at
    // the IF coherence point before tid0's arrival increment. Consumers read
    // ring data with coherent (sc0 sc1) loads after observing the release —
    // no cache maintenance (buffer_inv / buffer_wbl2) anywhere.
    __syncthreads();
    if (tid == 0) {
      const int target = s + 1;
      int* leafp = &bar->leaf[(wg >> 4) * 32];
      int* gepp  = &bar->gep[(wg >> 4) * 32];
      int prev = __hip_atomic_fetch_add(leafp, 1, __ATOMIC_RELAXED, __HIP_MEMORY_SCOPE_AGENT);
      if ((prev & 15) == 15) {   // 16th arrival of this slot in this group
        int r = __hip_atomic_fetch_add(&bar->root, 1, __ATOMIC_RELAXED, __HIP_MEMORY_SCOPE_AGENT);
        if ((r & 15) == 15) {    // 16th group — release everyone
          __hip_atomic_store(&bar->epoch, target, __ATOMIC_RELAXED, __HIP_MEMORY_SCOPE_AGENT);
        } else {
          while (__hip_atomic_load(&bar->epoch, __ATOMIC_RELAXED, __HIP_MEMORY_SCOPE_AGENT) < target)
            __builtin_amdgcn_s_sleep(1);
        }
        __hip_atomic_store(gepp, target, __ATOMIC_RELAXED, __HIP_MEMORY_SCOPE_AGENT);
      } else {
        while (__hip_atomic_load(gepp, __ATOMIC_RELAXED, __HIP_MEMORY_SCOPE_AGENT) < target)
          __builtin_amdgcn_s_sleep(1);
      }
    }
    __syncthreads();
  }
}

extern "C" void kernel_launch(void* const* d_in, const int* in_sizes, int n_in,
                              void* d_out, int out_size, void* d_ws, size_t ws_size,
                              hipStream_t stream) {
  const int*   src  = (const int*)d_in[0];
  const int*   slen = (const int*)d_in[1];
  const float* emb  = (const float*)d_in[2];
  const float* Wih0 = (const float*)d_in[3];
  const float* Whh0 = (const float*)d_in[4];
  const float* bih0 = (const float*)d_in[5];
  const float* bhh0 = (const float*)d_in[6];
  const float* Wih1 = (const float*)d_in[7];
  const float* Whh1 = (const float*)d_in[8];
  const float* bih1 = (const float*)d_in[9];
  const float* bhh1 = (const float*)d_in[10];
  float* out = (float*)d_out;

  int*   bar    = (int*)d_ws;
  float* h0ring = (float*)((char*)d_ws + 8192);
  float* h1ring = h0ring + 2 * RING_SLOT;

  // zero barrier state + all 4 ring slots (ws is poisoned 0xAA before every launch)
  int zero_ints = (8192 + 4 * RING_SLOT * 4) / 4;
  hipLaunchKernelGGL(init_ws_kernel, dim3(64), dim3(256), 0, stream, (int*)d_ws, zero_ints);

  // 128 KB weights + 16 KB partials = 144 KB dynamic LDS (1 WG/CU)
  (void)hipFuncSetAttribute((const void*)lstm_pipe,
                            hipFuncAttributeMaxDynamicSharedMemorySize, 147456);

  hipLaunchKernelGGL(lstm_pipe, dim3(NWG), dim3(TPB), 147456, stream,
                     src, slen, emb, Wih0, Whh0, bih0, bhh0, Wih1, Whh1, bih1, bhh1,
                     out, bar, h0ring, h1ring);
}